// Round 3
// baseline (931.312 us; speedup 1.0000x reference)
//
#include <hip/hip_runtime.h>

#define HW   36864      // 192*192
#define NPOS 73728      // B*HW, B=2
#define EPSV 1e-5f

// channel-slot layout in workspace (each slot = NPOS floats)
#define S1_HF1  0
#define S1_FD1  20
#define S1_PHU1 50
#define S1_PHL1 70
#define S1_HD1  90
#define S2_HF2  160
#define S2_FD2  170
#define S2_PHU2 200
#define S2_PHL2 210
#define S2_HD2  220
#define S3_FU   0       // reuse stage-1 slots (dead by stage 3)
#define S3_HU   20
#define S3_PU   50
#define ST3_FU  290     // stat-channel bases for stage 3
#define ST3_HU  310
#define ST3_PU  340
#define NSLOT 290
#define NSTAT 410

__device__ __forceinline__ float4 ld4(const float* p) { return *(const float4*)p; }

__device__ __forceinline__ void fma4(float4& a, float w, const float4& x) {
    a.x = fmaf(w, x.x, a.x); a.y = fmaf(w, x.y, a.y);
    a.z = fmaf(w, x.z, a.z); a.w = fmaf(w, x.w, a.w);
}

__device__ __forceinline__ float4 bnrelu4(float4 v, float sc, float sh) {
    float4 r;
    r.x = fmaf(v.x, sc, sh); r.y = fmaf(v.y, sc, sh);
    r.z = fmaf(v.z, sc, sh); r.w = fmaf(v.w, sc, sh);
    r.x = r.x > 0.f ? r.x : 0.f; r.y = r.y > 0.f ? r.y : 0.f;
    r.z = r.z > 0.f ? r.z : 0.f; r.w = r.w > 0.f ? r.w : 0.f;
    return r;
}

__device__ __forceinline__ void preload(const float* __restrict__ g, float* l, int n) {
    for (int i = threadIdx.x; i < n; i += 256) l[i] = g[i];
}

// ---------------------------------------------------------------------------
// conv: 4 positions/thread (float4), weights LDS-resident (broadcast reads),
// CH=8 channel prefetch pipeline. CIN is always even -> pair processing.
// ---------------------------------------------------------------------------
template<int CIN, int COUT, class F>
__device__ __forceinline__ void conv4(F fetch, const float* wl,
                                      float* __restrict__ y, int p,
                                      float* __restrict__ sumA,
                                      float* __restrict__ sumqA,
                                      int stat0, float* red)
{
    float4 acc[COUT];
#pragma unroll
    for (int o = 0; o < COUT; ++o) acc[o] = make_float4(0.f, 0.f, 0.f, 0.f);

    constexpr int CH = 8;
    constexpr int MAIN = (CIN / CH) * CH;
    if (MAIN > 0) {
        float4 buf[CH];
#pragma unroll
        for (int i = 0; i < CH; ++i) buf[i] = fetch(i);
#pragma unroll 1
        for (int c0 = CH; c0 < MAIN; c0 += CH) {
            float4 nxt[CH];
#pragma unroll
            for (int i = 0; i < CH; ++i) nxt[i] = fetch(c0 + i);   // prefetch
            const int cb = c0 - CH;
#pragma unroll
            for (int i = 0; i < CH; i += 2) {
#pragma unroll
                for (int o = 0; o < COUT; ++o) {
                    float2 wp = *(const float2*)(wl + o * CIN + cb + i);
                    fma4(acc[o], wp.x, buf[i]);
                    fma4(acc[o], wp.y, buf[i + 1]);
                }
            }
#pragma unroll
            for (int i = 0; i < CH; ++i) buf[i] = nxt[i];
        }
        const int cb = MAIN - CH;
#pragma unroll
        for (int i = 0; i < CH; i += 2) {
#pragma unroll
            for (int o = 0; o < COUT; ++o) {
                float2 wp = *(const float2*)(wl + o * CIN + cb + i);
                fma4(acc[o], wp.x, buf[i]);
                fma4(acc[o], wp.y, buf[i + 1]);
            }
        }
    }
#pragma unroll
    for (int c = MAIN; c < CIN; c += 2) {   // tail (CIN always even)
        float4 x0 = fetch(c), x1 = fetch(c + 1);
#pragma unroll
        for (int o = 0; o < COUT; ++o) {
            float2 wp = *(const float2*)(wl + o * CIN + c);
            fma4(acc[o], wp.x, x0);
            fma4(acc[o], wp.y, x1);
        }
    }

#pragma unroll
    for (int o = 0; o < COUT; ++o)
        *(float4*)(y + (size_t)o * NPOS + p) = acc[o];

    int lane = threadIdx.x & 63;
    int wv_  = threadIdx.x >> 6;
#pragma unroll
    for (int o = 0; o < COUT; ++o) {
        float s = acc[o].x + acc[o].y + acc[o].z + acc[o].w;
        float q = acc[o].x * acc[o].x + acc[o].y * acc[o].y
                + acc[o].z * acc[o].z + acc[o].w * acc[o].w;
#pragma unroll
        for (int i = 1; i < 64; i <<= 1) {
            s += __shfl_xor(s, i, 64);
            q += __shfl_xor(q, i, 64);
        }
        if (lane == 0) {
            red[(wv_ * COUT + o) * 2]     = s;
            red[(wv_ * COUT + o) * 2 + 1] = q;
        }
    }
    __syncthreads();
    if (threadIdx.x < COUT) {
        int o = threadIdx.x;
        float s = 0.f, q = 0.f;
#pragma unroll
        for (int k = 0; k < 4; ++k) {
            s += red[(k * COUT + o) * 2];
            q += red[(k * COUT + o) * 2 + 1];
        }
        atomicAdd(&sumA[stat0 + o], s);
        atomicAdd(&sumqA[stat0 + o], q);
    }
}

// ---------------------------------------------------------------------------
// Stage 1: hf1 | fd1(15+15) | phu1 | phl1 | hd1(20+20+15+15)  -> 9 slices
// ---------------------------------------------------------------------------
__global__ void __launch_bounds__(256) stage1_kernel(
    const float* __restrict__ xp, const float* __restrict__ xh,
    const float* __restrict__ xf, const float* __restrict__ p_fea,
    const float* __restrict__ h_fea,
    const float* __restrict__ w_hf1, const float* __restrict__ w_fd1,
    const float* __restrict__ w_phu1, const float* __restrict__ w_phl1,
    const float* __restrict__ w_hd1, float* __restrict__ ws)
{
    __shared__ float wl[5520];          // max 20*276
    __shared__ float red[4 * 20 * 2];
    int g = blockIdx.x * 256 + threadIdx.x;
    int p = g * 4;
    int b = (p >= HW) ? 1 : 0;
    int s = p - b * HW;
    float* y     = ws;
    float* sumA  = ws + (size_t)NSLOT * NPOS;
    float* sumqA = sumA + NSTAT;

    switch (blockIdx.y) {
    case 0: { // hf1: [xh1;xh2](20) -> 20
        preload(w_hf1, wl, 20 * 20); __syncthreads();
        const float* xb = xh + ((size_t)b * 30 + 10) * HW + s;
        conv4<20, 20>([&](int c) { return ld4(xb + c * HW); },
                      wl, y + (size_t)S1_HF1 * NPOS, p, sumA, sumqA, S1_HF1, red);
        break; }
    case 1: case 2: { // fd1: [h_fea;xf1](266) -> 15+15
        int off = (blockIdx.y - 1) * 15;
        preload(w_fd1 + off * 266, wl, 15 * 266); __syncthreads();
        const float* hb  = h_fea + (size_t)b * 256 * HW + s;
        const float* xf1 = xf + ((size_t)b * 20 + 10) * HW + s;
        conv4<266, 15>([&](int c) { return (c < 256) ? ld4(hb + c * HW)
                                                     : ld4(xf1 + (c - 256) * HW); },
                       wl, y + (size_t)(S1_FD1 + off) * NPOS, p,
                       sumA, sumqA, S1_FD1 + off, red);
        break; }
    case 3: { // phu1: xp[1:5](40) -> 20
        preload(w_phu1, wl, 20 * 40); __syncthreads();
        const float* xb = xp + ((size_t)b * 70 + 10) * HW + s;
        conv4<40, 20>([&](int c) { return ld4(xb + c * HW); },
                      wl, y + (size_t)S1_PHU1 * NPOS, p, sumA, sumqA, S1_PHU1, red);
        break; }
    case 4: { // phl1: xp[5:7](20) -> 20
        preload(w_phl1, wl, 20 * 20); __syncthreads();
        const float* xb = xp + ((size_t)b * 70 + 50) * HW + s;
        conv4<20, 20>([&](int c) { return ld4(xb + c * HW); },
                      wl, y + (size_t)S1_PHL1 * NPOS, p, sumA, sumqA, S1_PHL1, red);
        break; }
    case 5: case 6: { // hd1: [p_fea;xh1;xh2](276) -> 20+20
        int off = (blockIdx.y - 5) * 20;
        preload(w_hd1 + off * 276, wl, 20 * 276); __syncthreads();
        const float* pb = p_fea + (size_t)b * 256 * HW + s;
        const float* xb = xh + ((size_t)b * 30 + 10) * HW + s;
        conv4<276, 20>([&](int c) { return (c < 256) ? ld4(pb + c * HW)
                                                     : ld4(xb + (c - 256) * HW); },
                       wl, y + (size_t)(S1_HD1 + off) * NPOS, p,
                       sumA, sumqA, S1_HD1 + off, red);
        break; }
    default: { // hd1: -> 15+15 (off 40,55)
        int off = 40 + (blockIdx.y - 7) * 15;
        preload(w_hd1 + off * 276, wl, 15 * 276); __syncthreads();
        const float* pb = p_fea + (size_t)b * 256 * HW + s;
        const float* xb = xh + ((size_t)b * 30 + 10) * HW + s;
        conv4<276, 15>([&](int c) { return (c < 256) ? ld4(pb + c * HW)
                                                     : ld4(xb + (c - 256) * HW); },
                       wl, y + (size_t)(S1_HD1 + off) * NPOS, p,
                       sumA, sumqA, S1_HD1 + off, red);
        break; }
    }
}

// ---------------------------------------------------------------------------
// scale/shift from accumulated stats
// ---------------------------------------------------------------------------
__global__ void scale_kernel(int stage,
    const float* __restrict__ bn_hf1, const float* __restrict__ bn_hf2,
    const float* __restrict__ bn_phu1, const float* __restrict__ bn_phu2,
    const float* __restrict__ bn_phl1, const float* __restrict__ bn_phl2,
    const float* __restrict__ bn_fd1, const float* __restrict__ bn_fd2,
    const float* __restrict__ bn_hd1, const float* __restrict__ bn_hd2,
    const float* __restrict__ bn_fu, const float* __restrict__ bn_hu,
    const float* __restrict__ bn_pu, float* __restrict__ ws)
{
    int t = threadIdx.x;
    float* sumA   = ws + (size_t)NSLOT * NPOS;
    float* sumqA  = sumA + NSTAT;
    float* scaleA = sumqA + NSTAT;
    float* shiftA = scaleA + NSTAT;
    int stat, local, co;
    const float* bn;
    if (stage == 1) {
        if (t >= 160) return;
        stat = t;
        if      (t < 20) { bn = bn_hf1;  local = t;      co = 20; }
        else if (t < 50) { bn = bn_fd1;  local = t - 20; co = 30; }
        else if (t < 70) { bn = bn_phu1; local = t - 50; co = 20; }
        else if (t < 90) { bn = bn_phl1; local = t - 70; co = 20; }
        else             { bn = bn_hd1;  local = t - 90; co = 70; }
    } else if (stage == 2) {
        if (t >= 130) return;
        stat = 160 + t;
        if      (t < 10) { bn = bn_hf2;  local = t;      co = 10; }
        else if (t < 40) { bn = bn_fd2;  local = t - 10; co = 30; }
        else if (t < 50) { bn = bn_phu2; local = t - 40; co = 10; }
        else if (t < 60) { bn = bn_phl2; local = t - 50; co = 10; }
        else             { bn = bn_hd2;  local = t - 60; co = 70; }
    } else {
        if (t >= 120) return;
        stat = 290 + t;
        if      (t < 20) { bn = bn_fu; local = t;      co = 20; }
        else if (t < 50) { bn = bn_hu; local = t - 20; co = 30; }
        else             { bn = bn_pu; local = t - 50; co = 70; }
    }
    float n  = (float)NPOS;
    float m  = sumA[stat] / n;
    float v  = sumqA[stat] / n - m * m;
    float g  = bn[local];
    float bt = bn[co + local];
    float sc = g * rsqrtf(v + EPSV);
    scaleA[stat] = sc;
    shiftA[stat] = bt - m * sc;
}

// ---------------------------------------------------------------------------
// Stage 2: hf2 | fd2(15+15) | phu2 | phl2 | hd2(20+20+15+15) -> 9 slices
// bn scale/shift for stats [0,160) preloaded to LDS.
// ---------------------------------------------------------------------------
__global__ void __launch_bounds__(256) stage2_kernel(
    const float* __restrict__ w_hf2, const float* __restrict__ w_fd2,
    const float* __restrict__ w_phu2, const float* __restrict__ w_phl2,
    const float* __restrict__ w_hd2, float* __restrict__ ws)
{
    __shared__ float wl[1400];          // max 20*70
    __shared__ float red[4 * 20 * 2];
    __shared__ float ssc[160], ssh[160];
    int g = blockIdx.x * 256 + threadIdx.x;
    int p = g * 4;
    float* y     = ws;
    float* sumA  = ws + (size_t)NSLOT * NPOS;
    float* sumqA = sumA + NSTAT;
    const float* scaleA = sumqA + NSTAT;
    const float* shiftA = scaleA + NSTAT;
    if (threadIdx.x < 160) {
        ssc[threadIdx.x] = scaleA[threadIdx.x];
        ssh[threadIdx.x] = shiftA[threadIdx.x];
    }

    switch (blockIdx.y) {
    case 0: { // hf2: hf1(20) -> 10
        preload(w_hf2, wl, 10 * 20); __syncthreads();
        const float* src = y + (size_t)S1_HF1 * NPOS + p;
        conv4<20, 10>([&](int c) {
            return bnrelu4(ld4(src + (size_t)c * NPOS), ssc[S1_HF1 + c], ssh[S1_HF1 + c]); },
            wl, y + (size_t)S2_HF2 * NPOS, p, sumA, sumqA, S2_HF2, red);
        break; }
    case 1: case 2: { // fd2: fd1(30) -> 15+15
        int off = (blockIdx.y - 1) * 15;
        preload(w_fd2 + off * 30, wl, 15 * 30); __syncthreads();
        const float* src = y + (size_t)S1_FD1 * NPOS + p;
        conv4<30, 15>([&](int c) {
            return bnrelu4(ld4(src + (size_t)c * NPOS), ssc[S1_FD1 + c], ssh[S1_FD1 + c]); },
            wl, y + (size_t)(S2_FD2 + off) * NPOS, p, sumA, sumqA, S2_FD2 + off, red);
        break; }
    case 3: { // phu2: phu1(20) -> 10
        preload(w_phu2, wl, 10 * 20); __syncthreads();
        const float* src = y + (size_t)S1_PHU1 * NPOS + p;
        conv4<20, 10>([&](int c) {
            return bnrelu4(ld4(src + (size_t)c * NPOS), ssc[S1_PHU1 + c], ssh[S1_PHU1 + c]); },
            wl, y + (size_t)S2_PHU2 * NPOS, p, sumA, sumqA, S2_PHU2, red);
        break; }
    case 4: { // phl2: phl1(20) -> 10
        preload(w_phl2, wl, 10 * 20); __syncthreads();
        const float* src = y + (size_t)S1_PHL1 * NPOS + p;
        conv4<20, 10>([&](int c) {
            return bnrelu4(ld4(src + (size_t)c * NPOS), ssc[S1_PHL1 + c], ssh[S1_PHL1 + c]); },
            wl, y + (size_t)S2_PHL2 * NPOS, p, sumA, sumqA, S2_PHL2, red);
        break; }
    case 5: case 6: { // hd2: hd1(70) -> 20+20
        int off = (blockIdx.y - 5) * 20;
        preload(w_hd2 + off * 70, wl, 20 * 70); __syncthreads();
        const float* src = y + (size_t)S1_HD1 * NPOS + p;
        conv4<70, 20>([&](int c) {
            return bnrelu4(ld4(src + (size_t)c * NPOS), ssc[S1_HD1 + c], ssh[S1_HD1 + c]); },
            wl, y + (size_t)(S2_HD2 + off) * NPOS, p, sumA, sumqA, S2_HD2 + off, red);
        break; }
    default: { // hd2 -> 15+15 (off 40,55)
        int off = 40 + (blockIdx.y - 7) * 15;
        preload(w_hd2 + off * 70, wl, 15 * 70); __syncthreads();
        const float* src = y + (size_t)S1_HD1 * NPOS + p;
        conv4<70, 15>([&](int c) {
            return bnrelu4(ld4(src + (size_t)c * NPOS), ssc[S1_HD1 + c], ssh[S1_HD1 + c]); },
            wl, y + (size_t)(S2_HD2 + off) * NPOS, p, sumA, sumqA, S2_HD2 + off, red);
        break; }
    }
}

// ---------------------------------------------------------------------------
// Stage 3: fu | hu(15+15) | pu(20+20+15+15) -> 7 slices
// bn scale/shift for stats [160,290) preloaded to LDS (index = stat-160).
// ---------------------------------------------------------------------------
__global__ void __launch_bounds__(256) stage3_kernel(
    const float* __restrict__ xp, const float* __restrict__ xh,
    const float* __restrict__ xf, const float* __restrict__ p_fea,
    const float* __restrict__ h_fea, const float* __restrict__ f_fea,
    const float* __restrict__ w_fu, const float* __restrict__ w_hu,
    const float* __restrict__ w_pu, float* __restrict__ ws)
{
    __shared__ float wl[6320];          // max 20*316
    __shared__ float red[4 * 20 * 2];
    __shared__ float ssc[130], ssh[130];
    int g = blockIdx.x * 256 + threadIdx.x;
    int p = g * 4;
    int b = (p >= HW) ? 1 : 0;
    int s = p - b * HW;
    float* y     = ws;
    float* sumA  = ws + (size_t)NSLOT * NPOS;
    float* sumqA = sumA + NSTAT;
    const float* scaleA = sumqA + NSTAT;
    const float* shiftA = scaleA + NSTAT;
    if (threadIdx.x < 130) {
        ssc[threadIdx.x] = scaleA[160 + threadIdx.x];
        ssh[threadIdx.x] = shiftA[160 + threadIdx.x];
    }

    switch (blockIdx.y) {
    case 0: { // fu: [f_fea; xf_new](266) -> 20 ; xf_new = bnrelu(hf2)+xf1
        preload(w_fu, wl, 20 * 266); __syncthreads();
        const float* fb   = f_fea + (size_t)b * 256 * HW + s;
        const float* yhf2 = y + (size_t)S2_HF2 * NPOS + p;
        const float* xf1  = xf + ((size_t)b * 20 + 10) * HW + s;
        conv4<266, 20>([&](int c) {
            if (c < 256) return ld4(fb + c * HW);
            int cc = c - 256;
            float4 v = bnrelu4(ld4(yhf2 + (size_t)cc * NPOS), ssc[cc], ssh[cc]); // S2_HF2-160=0
            float4 r0 = ld4(xf1 + cc * HW);
            return make_float4(v.x + r0.x, v.y + r0.y, v.z + r0.z, v.w + r0.w); },
            wl, y + (size_t)S3_FU * NPOS, p, sumA, sumqA, ST3_FU, red);
        break; }
    case 1: case 2: { // hu: [h_fea; xhu; xhl](276) -> 15+15
        int off = (blockIdx.y - 1) * 15;
        preload(w_hu + off * 276, wl, 15 * 276); __syncthreads();
        const float* hb    = h_fea + (size_t)b * 256 * HW + s;
        const float* yphu2 = y + (size_t)S2_PHU2 * NPOS + p;
        const float* yphl2 = y + (size_t)S2_PHL2 * NPOS + p;
        const float* yfd2  = y + (size_t)S2_FD2 * NPOS + p;
        const float* xh1b  = xh + ((size_t)b * 30 + 10) * HW + s;
        conv4<276, 15>([&](int c) {
            if (c < 256) return ld4(hb + c * HW);
            if (c < 266) {
                int cc = c - 256;
                float4 a = bnrelu4(ld4(yphu2 + (size_t)cc * NPOS),
                                   ssc[40 + cc], ssh[40 + cc]);          // S2_PHU2-160=40
                float4 f = bnrelu4(ld4(yfd2 + (size_t)(10 + cc) * NPOS),
                                   ssc[20 + cc], ssh[20 + cc]);          // S2_FD2-160+10=20
                float4 r0 = ld4(xh1b + cc * HW);
                return make_float4(r0.x + a.x + f.x, r0.y + a.y + f.y,
                                   r0.z + a.z + f.z, r0.w + a.w + f.w);
            }
            int cc = c - 266;
            float4 a = bnrelu4(ld4(yphl2 + (size_t)cc * NPOS),
                               ssc[50 + cc], ssh[50 + cc]);              // S2_PHL2-160=50
            float4 f = bnrelu4(ld4(yfd2 + (size_t)(20 + cc) * NPOS),
                               ssc[30 + cc], ssh[30 + cc]);              // S2_FD2-160+20=30
            float4 r0 = ld4(xh1b + (10 + cc) * HW);
            return make_float4(r0.x + a.x + f.x, r0.y + a.y + f.y,
                               r0.z + a.z + f.z, r0.w + a.w + f.w); },
            wl, y + (size_t)(S3_HU + off) * NPOS, p, sumA, sumqA, ST3_HU + off, red);
        break; }
    case 3: case 4: { // pu: [p_fea; xp_new(60)](316) -> 20+20
        int off = (blockIdx.y - 3) * 20;
        preload(w_pu + off * 316, wl, 20 * 316); __syncthreads();
        const float* pb   = p_fea + (size_t)b * 256 * HW + s;
        const float* yhd2 = y + (size_t)S2_HD2 * NPOS + p;
        const float* xpb  = xp + ((size_t)b * 70 + 10) * HW + s;
        conv4<316, 20>([&](int c) {
            if (c < 256) return ld4(pb + c * HW);
            int cc = c - 256;
            float4 v = bnrelu4(ld4(yhd2 + (size_t)(10 + cc) * NPOS),
                               ssc[70 + cc], ssh[70 + cc]);              // S2_HD2-160+10=70
            float4 r0 = ld4(xpb + cc * HW);
            return make_float4(v.x + r0.x, v.y + r0.y, v.z + r0.z, v.w + r0.w); },
            wl, y + (size_t)(S3_PU + off) * NPOS, p, sumA, sumqA, ST3_PU + off, red);
        break; }
    default: { // pu -> 15+15 (off 40,55)
        int off = 40 + (blockIdx.y - 5) * 15;
        preload(w_pu + off * 316, wl, 15 * 316); __syncthreads();
        const float* pb   = p_fea + (size_t)b * 256 * HW + s;
        const float* yhd2 = y + (size_t)S2_HD2 * NPOS + p;
        const float* xpb  = xp + ((size_t)b * 70 + 10) * HW + s;
        conv4<316, 15>([&](int c) {
            if (c < 256) return ld4(pb + c * HW);
            int cc = c - 256;
            float4 v = bnrelu4(ld4(yhd2 + (size_t)(10 + cc) * NPOS),
                               ssc[70 + cc], ssh[70 + cc]);
            float4 r0 = ld4(xpb + cc * HW);
            return make_float4(v.x + r0.x, v.y + r0.y, v.z + r0.z, v.w + r0.w); },
            wl, y + (size_t)(S3_PU + off) * NPOS, p, sumA, sumqA, ST3_PU + off, red);
        break; }
    }
}

// ---------------------------------------------------------------------------
// Final: bn+relu all 220 output channels, float4
// out = concat([xp_upd(70), xh_upd(30), xf_upd(20), xfh(30), xhp(70)])
// ---------------------------------------------------------------------------
__global__ void __launch_bounds__(256) final_kernel(const float* __restrict__ ws,
                                                    float* __restrict__ out)
{
    int g = blockIdx.x * 256 + threadIdx.x;
    int p = g * 4;
    int c = blockIdx.y;
    const float* sumA   = ws + (size_t)NSLOT * NPOS;
    const float* scaleA = sumA + 2 * NSTAT;
    const float* shiftA = scaleA + NSTAT;
    int slot, stat;
    if      (c < 70)  { slot = S3_PU  + c;         stat = ST3_PU  + c;         }
    else if (c < 100) { slot = S3_HU  + (c - 70);  stat = ST3_HU  + (c - 70);  }
    else if (c < 120) { slot = S3_FU  + (c - 100); stat = ST3_FU  + (c - 100); }
    else if (c < 150) { slot = S2_FD2 + (c - 120); stat = S2_FD2 + (c - 120);  }
    else              { slot = S2_HD2 + (c - 150); stat = S2_HD2 + (c - 150);  }
    float4 v = *(const float4*)(ws + (size_t)slot * NPOS + p);
    float sc = scaleA[stat], sh = shiftA[stat];
    v.x = fmaf(v.x, sc, sh); v.x = v.x > 0.f ? v.x : 0.f;
    v.y = fmaf(v.y, sc, sh); v.y = v.y > 0.f ? v.y : 0.f;
    v.z = fmaf(v.z, sc, sh); v.z = v.z > 0.f ? v.z : 0.f;
    v.w = fmaf(v.w, sc, sh); v.w = v.w > 0.f ? v.w : 0.f;
    int b = (p >= HW) ? 1 : 0;
    int s = p - b * HW;
    *(float4*)(out + ((size_t)b * 220 + c) * HW + s) = v;
}

// ---------------------------------------------------------------------------
extern "C" void kernel_launch(void* const* d_in, const int* in_sizes, int n_in,
                              void* d_out, int out_size, void* d_ws, size_t ws_size,
                              hipStream_t stream)
{
    const float* xp     = (const float*)d_in[0];
    const float* xh     = (const float*)d_in[1];
    const float* xf     = (const float*)d_in[2];
    const float* p_fea  = (const float*)d_in[3];
    const float* h_fea  = (const float*)d_in[4];
    const float* f_fea  = (const float*)d_in[5];
    const float* w_hf1  = (const float*)d_in[6];  const float* bn_hf1  = (const float*)d_in[7];
    const float* w_hf2  = (const float*)d_in[8];  const float* bn_hf2  = (const float*)d_in[9];
    const float* w_phu1 = (const float*)d_in[10]; const float* bn_phu1 = (const float*)d_in[11];
    const float* w_phu2 = (const float*)d_in[12]; const float* bn_phu2 = (const float*)d_in[13];
    const float* w_phl1 = (const float*)d_in[14]; const float* bn_phl1 = (const float*)d_in[15];
    const float* w_phl2 = (const float*)d_in[16]; const float* bn_phl2 = (const float*)d_in[17];
    const float* w_fd1  = (const float*)d_in[18]; const float* bn_fd1  = (const float*)d_in[19];
    const float* w_fd2  = (const float*)d_in[20]; const float* bn_fd2  = (const float*)d_in[21];
    const float* w_hd1  = (const float*)d_in[22]; const float* bn_hd1  = (const float*)d_in[23];
    const float* w_hd2  = (const float*)d_in[24]; const float* bn_hd2  = (const float*)d_in[25];
    const float* w_fu   = (const float*)d_in[26]; const float* bn_fu   = (const float*)d_in[27];
    const float* w_hu   = (const float*)d_in[28]; const float* bn_hu   = (const float*)d_in[29];
    const float* w_pu   = (const float*)d_in[30]; const float* bn_pu   = (const float*)d_in[31];

    float* ws  = (float*)d_ws;
    float* out = (float*)d_out;

    size_t need_bytes = ((size_t)NSLOT * NPOS + 4 * NSTAT) * sizeof(float);
    if (ws_size < need_bytes) return;

    hipMemsetAsync(ws + (size_t)NSLOT * NPOS, 0, 2 * NSTAT * sizeof(float), stream);

    dim3 blk(256);
    const int GX = NPOS / 1024;   // 72 blocks, 4 positions/thread
    stage1_kernel<<<dim3(GX, 9), blk, 0, stream>>>(xp, xh, xf, p_fea, h_fea,
                                                   w_hf1, w_fd1, w_phu1, w_phl1, w_hd1, ws);
    scale_kernel<<<1, 256, 0, stream>>>(1, bn_hf1, bn_hf2, bn_phu1, bn_phu2, bn_phl1, bn_phl2,
                                        bn_fd1, bn_fd2, bn_hd1, bn_hd2, bn_fu, bn_hu, bn_pu, ws);
    stage2_kernel<<<dim3(GX, 9), blk, 0, stream>>>(w_hf2, w_fd2, w_phu2, w_phl2, w_hd2, ws);
    scale_kernel<<<1, 256, 0, stream>>>(2, bn_hf1, bn_hf2, bn_phu1, bn_phu2, bn_phl1, bn_phl2,
                                        bn_fd1, bn_fd2, bn_hd1, bn_hd2, bn_fu, bn_hu, bn_pu, ws);
    stage3_kernel<<<dim3(GX, 7), blk, 0, stream>>>(xp, xh, xf, p_fea, h_fea, f_fea,
                                                   w_fu, w_hu, w_pu, ws);
    scale_kernel<<<1, 256, 0, stream>>>(3, bn_hf1, bn_hf2, bn_phu1, bn_phu2, bn_phl1, bn_phl2,
                                        bn_fd1, bn_fd2, bn_hd1, bn_hd2, bn_fu, bn_hu, bn_pu, ws);
    final_kernel<<<dim3(GX, 220), blk, 0, stream>>>(ws, out);
}